// Round 8
// baseline (210.753 us; speedup 1.0000x reference)
//
#include <hip/hip_runtime.h>
#include <math.h>

#define MM 16384
#define NN 8192
#define DD 128

#define L2E  1.4426950408889634f
#define COEF 0.15915494309189535f   // 1/(2*pi)

// ---------------------------------------------------------------------------
// bf16 helpers (RNE)
// ---------------------------------------------------------------------------
__device__ __forceinline__ unsigned short f2bf(float f) {
    unsigned u = __float_as_uint(f);
    u = (u + 0x7FFFu + ((u >> 16) & 1u)) >> 16;
    return (unsigned short)u;
}
__device__ __forceinline__ float bf2f(unsigned short h) {
    return __uint_as_float((unsigned)h << 16);
}

__device__ __forceinline__ void async16(short* lds, const short* g) {
    __builtin_amdgcn_global_load_lds(
        (const __attribute__((address_space(1))) unsigned int*)g,
        (__attribute__((address_space(3))) unsigned int*)lds,
        16, 0, 0);
}

typedef __attribute__((ext_vector_type(8))) short bf16x8;
typedef __attribute__((ext_vector_type(4))) float f32x4;

// ---------------------------------------------------------------------------
// Pre-pass v2: one wave per 16-row block, perfectly-coalesced stores.
// Layout (unchanged from round 7): Cat = [rowblock rb][phase 0..11][64
// granules of 16B], granule (rp,g) at slot rp*4+((g+(rp>>1))&3) (bank
// swizzle for conflict-free ds_read_b128 after DMA).
// Lane l owns granule (rp=l>>2, g=((l&3)-(rp>>1))&3)  -> slot(rp,g)==l, so
// each phase store is ONE contiguous 1KB uint4 store per wave.
// Sections: A phases 0-3=hi(x*L2E), 4-7=lo, 8-11=hi ; B: hi, hi, lo.
// xc[m] = -0.5|x|^2*L2E ; mc[n] = (ln w - 0.5|mu|^2)*L2E
// ---------------------------------------------------------------------------
__global__ __launch_bounds__(256) void gmm_prep_bf16(
    const float* __restrict__ x, const float* __restrict__ means,
    const float* __restrict__ w, short* __restrict__ Acat,
    short* __restrict__ Bcat, float* __restrict__ xc, float* __restrict__ mc)
{
    const int l    = threadIdx.x & 63;
    const int rbk  = blockIdx.x * 4 + (threadIdx.x >> 6);   // 0..1535
    const bool isx = rbk < (MM / 16);
    const int rb   = isx ? rbk : rbk - (MM / 16);
    const int rp   = l >> 2;
    const int g    = ((l & 3) - (rp >> 1)) & 3;
    const int row  = rb * 16 + rp;

    const float* src = (isx ? x : means) + (size_t)row * DD + g * 8;

    float ss = 0.f;
    uint4 HI[4], LO[4];
    #pragma unroll
    for (int c4 = 0; c4 < 4; ++c4) {
        float4 u0 = *(const float4*)(src + c4 * 32);
        float4 u1 = *(const float4*)(src + c4 * 32 + 4);
        float a[8] = {u0.x, u0.y, u0.z, u0.w, u1.x, u1.y, u1.z, u1.w};
        unsigned hi[4], lo[4];
        #pragma unroll
        for (int p = 0; p < 4; ++p) {
            ss = fmaf(a[2 * p], a[2 * p], fmaf(a[2 * p + 1], a[2 * p + 1], ss));
            float a0 = isx ? a[2 * p] * L2E     : a[2 * p];
            float a1 = isx ? a[2 * p + 1] * L2E : a[2 * p + 1];
            unsigned short h0 = f2bf(a0), h1 = f2bf(a1);
            unsigned short l0 = f2bf(a0 - bf2f(h0)), l1 = f2bf(a1 - bf2f(h1));
            hi[p] = (unsigned)h0 | ((unsigned)h1 << 16);
            lo[p] = (unsigned)l0 | ((unsigned)l1 << 16);
        }
        HI[c4] = make_uint4(hi[0], hi[1], hi[2], hi[3]);
        LO[c4] = make_uint4(lo[0], lo[1], lo[2], lo[3]);
    }

    short* base = (isx ? Acat : Bcat) + (size_t)rb * 6144 + l * 8;
    #pragma unroll
    for (int p = 0; p < 4; ++p) {
        *(uint4*)(base + p * 512)       = HI[p];              // phases 0..3
        *(uint4*)(base + (p + 4) * 512) = isx ? LO[p] : HI[p]; // 4..7
        *(uint4*)(base + (p + 8) * 512) = isx ? HI[p] : LO[p]; // 8..11
    }

    // lanes rp*4..rp*4+3 hold the 4 column-quarters of one row
    ss += __shfl_xor(ss, 1, 64);
    ss += __shfl_xor(ss, 2, 64);
    if ((l & 3) == 0) {
        if (isx) xc[row] = -0.5f * ss * L2E;
        else     mc[row] = (logf(w[row]) - 0.5f * ss) * L2E;
    }
}

// ---------------------------------------------------------------------------
// Main MFMA kernel — TRIPLE-buffered staging with non-draining barriers.
// Per phase k: asm "s_waitcnt vmcnt(4); s_barrier" drains only the DMA
// issued at phase k-2 (phase k+1's 4 loads stay in flight), then issues
// phase k+2 into buffer (k+2)%3, then ds_read/MFMA on buffer k%3.
// Safety: DMA for k+2 is issued after the barrier -> buffer (k+2)%3's
// readers (phase k-1) are all done (reads complete before their MFMA).
// Any compiler-inserted extra waitcnt only over-synchronizes (correct).
// 128x128 tile, 4 waves 2x2, 12 phases of BK=32 (3-pass hi/lo bf16 split),
// swizzled conflict-free LDS (round 7). LDS 49.5KB -> 3 blocks/CU (256,3).
// Epilogue: exp2(acc + xc + mc), width-16 shuffle reduce, partials store.
// ---------------------------------------------------------------------------
__global__ __launch_bounds__(256, 3) void gmm_mfma(
    const short* __restrict__ Acat, const short* __restrict__ Bcat,
    const float* __restrict__ xc, const float* __restrict__ mc,
    float* __restrict__ partials)
{
    __shared__ __align__(16) short As[3][4096];   // 3 x 8 KB
    __shared__ __align__(16) short Bs[3][4096];   // 3 x 8 KB
    __shared__ __align__(16) float xcs[128];
    __shared__ float red[2][128];

    const int tid  = threadIdx.x;
    const int w    = tid >> 6, lane = tid & 63;
    const int wm   = w >> 1,   wn   = w & 1;
    const int quad = lane >> 4, col = lane & 15;
    const int m0   = blockIdx.x * 128;
    const int nb   = blockIdx.y * 128;

    const short* ga0 = Acat + (size_t)(blockIdx.x * 8 + w * 2) * 6144 + lane * 8;
    const short* ga1 = ga0 + 6144;
    const short* gb0 = Bcat + (size_t)(blockIdx.y * 8 + w * 2) * 6144 + lane * 8;
    const short* gb1 = gb0 + 6144;
    const int lofs0 = w * 1024;
    const int lofs1 = w * 1024 + 512;

    // xcs staged FIRST so its load's waitcnt drains before any DMA is issued
    if (tid < 128) xcs[tid] = xc[m0 + tid];

    // prologue: stage phases 0 and 1
    async16(&As[0][lofs0], ga0);
    async16(&As[0][lofs1], ga1);
    async16(&Bs[0][lofs0], gb0);
    async16(&Bs[0][lofs1], gb1);
    async16(&As[1][lofs0], ga0 + 512);
    async16(&As[1][lofs1], ga1 + 512);
    async16(&Bs[1][lofs0], gb0 + 512);
    async16(&Bs[1][lofs1], gb1 + 512);

    f32x4 acc[4][4];
    #pragma unroll
    for (int i = 0; i < 4; ++i)
        #pragma unroll
        for (int j = 0; j < 4; ++j)
            acc[i][j] = (f32x4){0.f, 0.f, 0.f, 0.f};

    // swizzled in-tile read offset (shorts): r'=col, g=quad
    const int rdo = col * 32 + ((quad + (col >> 1)) & 3) * 8;

    #pragma unroll
    for (int ks = 0; ks < 12; ++ks) {
        // non-draining barrier: keep the newest 4 loads (phase ks+1) in
        // flight; drain phase ks (issued two iterations ago). Last phase
        // has only its own 4 outstanding -> full drain.
        if (ks == 11) asm volatile("s_waitcnt vmcnt(0)\n\ts_barrier" ::: "memory");
        else          asm volatile("s_waitcnt vmcnt(4)\n\ts_barrier" ::: "memory");

        if (ks < 10) {
            const int b2 = (ks + 2) % 3;
            const int ko = (ks + 2) * 512;
            async16(&As[b2][lofs0], ga0 + ko);
            async16(&As[b2][lofs1], ga1 + ko);
            async16(&Bs[b2][lofs0], gb0 + ko);
            async16(&Bs[b2][lofs1], gb1 + ko);
        }

        const int buf = ks % 3;
        bf16x8 af[4];
        #pragma unroll
        for (int i = 0; i < 4; ++i)
            af[i] = *(const bf16x8*)(&As[buf][(wm * 4 + i) * 512 + rdo]);
        #pragma unroll
        for (int j = 0; j < 4; ++j) {
            bf16x8 bfr = *(const bf16x8*)(&Bs[buf][(wn * 4 + j) * 512 + rdo]);
            #pragma unroll
            for (int i = 0; i < 4; ++i)
                acc[i][j] = __builtin_amdgcn_mfma_f32_16x16x32_bf16(
                    af[i], bfr, acc[i][j], 0, 0, 0);
        }
    }

    // epilogue: C/D layout col = lane&15, row = quad*4 + reg
    float mcv[4];
    #pragma unroll
    for (int j = 0; j < 4; ++j) mcv[j] = mc[nb + wn * 64 + j * 16 + col];

    #pragma unroll
    for (int i = 0; i < 4; ++i) {
        float4 xv = *(const float4*)&xcs[wm * 64 + i * 16 + quad * 4];
        float xa[4] = {xv.x, xv.y, xv.z, xv.w};
        #pragma unroll
        for (int r = 0; r < 4; ++r) {
            float s = 0.f;
            #pragma unroll
            for (int j = 0; j < 4; ++j)
                s += __builtin_exp2f(acc[i][j][r] + xa[r] + mcv[j]);
            s += __shfl_xor(s, 1, 16);
            s += __shfl_xor(s, 2, 16);
            s += __shfl_xor(s, 4, 16);
            s += __shfl_xor(s, 8, 16);
            if (col == 0) red[wn][wm * 64 + i * 16 + quad * 4 + r] = s;
        }
    }
    __syncthreads();
    if (tid < 128)
        partials[(size_t)blockIdx.y * MM + m0 + tid] = red[0][tid] + red[1][tid];
}

__global__ __launch_bounds__(256) void gmm_reduce(
    const float* __restrict__ partials, float* __restrict__ out)
{
    int m = blockIdx.x * 256 + threadIdx.x;
    float s = 0.f;
    #pragma unroll 8
    for (int k = 0; k < 64; ++k) s += partials[(size_t)k * MM + m];
    out[m] = COEF * s;
}

// ===========================================================================
// Fallback fp32 path (round-1) — only if ws_size is too small.
// ===========================================================================
__global__ __launch_bounds__(256) void gmm_prep(
    const float* __restrict__ x, const float* __restrict__ means,
    const float* __restrict__ w, float* __restrict__ xc, float* __restrict__ mc)
{
    int tid = blockIdx.x * 256 + threadIdx.x;
    if (tid < MM) {
        const float4* row = (const float4*)(x + (size_t)tid * DD);
        float ss = 0.f;
        #pragma unroll
        for (int i = 0; i < DD / 4; ++i) {
            float4 v = row[i];
            ss = fmaf(v.x, v.x, fmaf(v.y, v.y, fmaf(v.z, v.z, fmaf(v.w, v.w, ss))));
        }
        xc[tid] = -0.5f * ss * L2E;
    } else if (tid < MM + NN) {
        int n = tid - MM;
        const float4* row = (const float4*)(means + (size_t)n * DD);
        float ss = 0.f;
        #pragma unroll
        for (int i = 0; i < DD / 4; ++i) {
            float4 v = row[i];
            ss = fmaf(v.x, v.x, fmaf(v.y, v.y, fmaf(v.z, v.z, fmaf(v.w, v.w, ss))));
        }
        mc[n] = (logf(w[n]) - 0.5f * ss) * L2E;
    }
}

__global__ __launch_bounds__(256, 2) void gmm_main(
    const float* __restrict__ x, const float* __restrict__ means,
    const float* __restrict__ xc, const float* __restrict__ mc,
    float* __restrict__ out)
{
    __shared__ __align__(16) float Asm[128 * 128];
    __shared__ __align__(16) float Bsm[2][16 * 128];

    const int t   = threadIdx.x;
    const int tc  = t & 15;
    const int tr  = t >> 4;
    const int r0  = blockIdx.x * 128;
    const int nq0 = blockIdx.y * 2048;

    {
        float4 tmp[16];
        #pragma unroll
        for (int ii = 0; ii < 16; ++ii) {
            int idx = t + ii * 256;
            int r   = idx >> 5;
            int k0  = (idx & 31) << 2;
            tmp[ii] = *(const float4*)(x + (size_t)(r0 + r) * DD + k0);
        }
        #pragma unroll
        for (int ii = 0; ii < 16; ++ii) {
            int idx = t + ii * 256;
            int r   = idx >> 5;
            int k0  = (idx & 31) << 2;
            int rb  = r >> 3, rl = r & 7;
            float v[4] = {tmp[ii].x, tmp[ii].y, tmp[ii].z, tmp[ii].w};
            #pragma unroll
            for (int j = 0; j < 4; ++j) {
                int k = k0 + j;
                Asm[k * 128 + (((rb ^ (k & 15)) << 3) | rl)] = v[j];
            }
        }
    }

    float xcv[8];
    {
        float4 a = *(const float4*)(xc + r0 + tr * 8);
        float4 b = *(const float4*)(xc + r0 + tr * 8 + 4);
        xcv[0] = a.x; xcv[1] = a.y; xcv[2] = a.z; xcv[3] = a.w;
        xcv[4] = b.x; xcv[5] = b.y; xcv[6] = b.z; xcv[7] = b.w;
    }

    float rowAcc[8];
    #pragma unroll
    for (int i = 0; i < 8; ++i) rowAcc[i] = 0.f;

    for (int ntile = 0; ntile < 16; ++ntile) {
        const int nbase = nq0 + ntile * 128;

        float acc[8][8];
        #pragma unroll
        for (int i = 0; i < 8; ++i)
            #pragma unroll
            for (int j = 0; j < 8; ++j) acc[i][j] = 0.f;

        float4 ld[2];
        #pragma unroll
        for (int ii = 0; ii < 2; ++ii) {
            int flat = t + ii * 256;
            int nl   = flat >> 2;
            int kl   = (flat & 3) << 2;
            ld[ii] = *(const float4*)(means + (size_t)(nbase + nl) * DD + kl);
        }

        for (int ks = 0; ks < 8; ++ks) {
            const int buf = ks & 1;
            #pragma unroll
            for (int ii = 0; ii < 2; ++ii) {
                int flat = t + ii * 256;
                int nl   = flat >> 2;
                int k0   = (flat & 3) << 2;
                int nbk  = nl >> 3, nll = nl & 7;
                float v[4] = {ld[ii].x, ld[ii].y, ld[ii].z, ld[ii].w};
                #pragma unroll
                for (int j = 0; j < 4; ++j) {
                    int kl = k0 + j;
                    Bsm[buf][kl * 128 + (((nbk ^ kl) << 3) | nll)] = v[j];
                }
            }
            if (ks < 7) {
                #pragma unroll
                for (int ii = 0; ii < 2; ++ii) {
                    int flat = t + ii * 256;
                    int nl   = flat >> 2;
                    int kl   = (flat & 3) << 2;
                    ld[ii] = *(const float4*)(means + (size_t)(nbase + nl) * DD
                                              + (ks + 1) * 16 + kl);
                }
            }
            __syncthreads();

            #pragma unroll
            for (int kk = 0; kk < 16; ++kk) {
                const int k = ks * 16 + kk;
                const float* apx = &Asm[k * 128 + ((tr ^ kk) << 3)];
                float4 a0 = *(const float4*)apx;
                float4 a1 = *(const float4*)(apx + 4);
                const float* bpx = &Bsm[buf][kk * 128 + ((tc ^ kk) << 3)];
                float4 b0 = *(const float4*)bpx;
                float4 b1 = *(const float4*)(bpx + 4);
                float av[8] = {a0.x, a0.y, a0.z, a0.w, a1.x, a1.y, a1.z, a1.w};
                float bv[8] = {b0.x, b0.y, b0.z, b0.w, b1.x, b1.y, b1.z, b1.w};
                #pragma unroll
                for (int i = 0; i < 8; ++i)
                    #pragma unroll
                    for (int j = 0; j < 8; ++j)
                        acc[i][j] = fmaf(av[i], bv[j], acc[i][j]);
            }
        }

        float mcv[8];
        {
            float4 a = *(const float4*)(mc + nbase + tc * 8);
            float4 b = *(const float4*)(mc + nbase + tc * 8 + 4);
            mcv[0] = a.x; mcv[1] = a.y; mcv[2] = a.z; mcv[3] = a.w;
            mcv[4] = b.x; mcv[5] = b.y; mcv[6] = b.z; mcv[7] = b.w;
        }
        #pragma unroll
        for (int i = 0; i < 8; ++i) {
            float s = 0.f;
            #pragma unroll
            for (int j = 0; j < 8; ++j) {
                float arg = fmaf(acc[i][j], L2E, xcv[i] + mcv[j]);
                s += __builtin_exp2f(arg);
            }
            rowAcc[i] += s;
        }
    }

    #pragma unroll
    for (int i = 0; i < 8; ++i) {
        float v = rowAcc[i];
        v += __shfl_xor(v, 1, 16);
        v += __shfl_xor(v, 2, 16);
        v += __shfl_xor(v, 4, 16);
        v += __shfl_xor(v, 8, 16);
        if (tc == 0) atomicAdd(out + r0 + tr * 8 + i, COEF * v);
    }
}

extern "C" void kernel_launch(void* const* d_in, const int* in_sizes, int n_in,
                              void* d_out, int out_size, void* d_ws, size_t ws_size,
                              hipStream_t stream) {
    const float* x     = (const float*)d_in[0];
    const float* means = (const float*)d_in[1];
    const float* w     = (const float*)d_in[2];
    float* out = (float*)d_out;

    const size_t needA = (size_t)MM * 384 * sizeof(short);   // 12.6 MB
    const size_t needB = (size_t)NN * 384 * sizeof(short);   //  6.3 MB
    const size_t need  = needA + needB + (size_t)(MM + NN) * 4
                       + (size_t)64 * MM * 4;                // + partials 4 MB

    if (ws_size >= need) {
        short* Acat     = (short*)d_ws;
        short* Bcat     = Acat + (size_t)MM * 384;
        float* xc       = (float*)(Bcat + (size_t)NN * 384);
        float* mc       = xc + MM;
        float* partials = mc + NN;
        gmm_prep_bf16<<<(MM + NN) / 64, 256, 0, stream>>>(x, means, w, Acat, Bcat, xc, mc);
        gmm_mfma<<<dim3(MM / 128, NN / 128), 256, 0, stream>>>(Acat, Bcat, xc, mc, partials);
        gmm_reduce<<<MM / 256, 256, 0, stream>>>(partials, out);
    } else {
        float* xc = (float*)d_ws;
        float* mc = xc + MM;
        hipMemsetAsync(out, 0, MM * sizeof(float), stream);
        gmm_prep<<<(MM + NN + 255) / 256, 256, 0, stream>>>(x, means, w, xc, mc);
        gmm_main<<<dim3(MM / 128, 4), 256, 0, stream>>>(x, means, xc, mc, out);
    }
}

// Round 9
// 176.753 us; speedup vs baseline: 1.1924x; 1.1924x over previous
//
#include <hip/hip_runtime.h>
#include <math.h>

#define MM 16384
#define NN 8192
#define DD 128

#define L2E  1.4426950408889634f
#define COEF 0.15915494309189535f   // 1/(2*pi)

// ---------------------------------------------------------------------------
// fp16 helpers (RNE via v_cvt_f16_f32)
// ---------------------------------------------------------------------------
__device__ __forceinline__ unsigned short f2h(float f) {
    _Float16 h = (_Float16)f;
    unsigned short u;
    __builtin_memcpy(&u, &h, 2);
    return u;
}
__device__ __forceinline__ float h2f(unsigned short u) {
    _Float16 h;
    __builtin_memcpy(&h, &u, 2);
    return (float)h;
}

__device__ __forceinline__ void async16(short* lds, const short* g) {
    __builtin_amdgcn_global_load_lds(
        (const __attribute__((address_space(1))) unsigned int*)g,
        (__attribute__((address_space(3))) unsigned int*)lds,
        16, 0, 0);
}

typedef __attribute__((ext_vector_type(8))) _Float16 f16x8;
typedef __attribute__((ext_vector_type(4))) float f32x4;

// ---------------------------------------------------------------------------
// Pre-pass (fp16 2-section, coalesced stores).
// Layout: Cat = [rowblock rb (16 rows)][phase 0..7][64 granules of 16B],
// granule (rp,g) at slot rp*4+((g+(rp>>1))&3) (bank swizzle so post-DMA LDS
// frag reads are conflict-free). Lane l owns (rp=l>>2, g=((l&3)-(rp>>1))&3)
// -> slot==l, so each phase store is ONE contiguous 1KB uint4 store per wave.
// Sections (K=256): A phases 0-3 = fp16_hi(x*L2E), 4-7 = fp16(residual);
//                   B phases 0-3 = fp16_hi(mu),    4-7 = fp16_hi(mu) (dup).
// dot = ah*bh + al*bh ~= (x*L2E).mu  (dropped a*bl ~ 2^-12 rel; threshold has
// ~1000x headroom per rounds 7/8 measurements).
// xc[m] = -0.5|x|^2*L2E ; mc[n] = (ln w - 0.5|mu|^2)*L2E
// ---------------------------------------------------------------------------
__global__ __launch_bounds__(256) void gmm_prep_f16(
    const float* __restrict__ x, const float* __restrict__ means,
    const float* __restrict__ w, short* __restrict__ Acat,
    short* __restrict__ Bcat, float* __restrict__ xc, float* __restrict__ mc)
{
    const int l    = threadIdx.x & 63;
    const int rbk  = blockIdx.x * 4 + (threadIdx.x >> 6);   // 0..1535
    const bool isx = rbk < (MM / 16);
    const int rb   = isx ? rbk : rbk - (MM / 16);
    const int rp   = l >> 2;
    const int g    = ((l & 3) - (rp >> 1)) & 3;
    const int row  = rb * 16 + rp;

    const float* src = (isx ? x : means) + (size_t)row * DD + g * 8;

    float ss = 0.f;
    uint4 HI[4], LO[4];
    #pragma unroll
    for (int c4 = 0; c4 < 4; ++c4) {
        float4 u0 = *(const float4*)(src + c4 * 32);
        float4 u1 = *(const float4*)(src + c4 * 32 + 4);
        float a[8] = {u0.x, u0.y, u0.z, u0.w, u1.x, u1.y, u1.z, u1.w};
        unsigned hi[4], lo[4];
        #pragma unroll
        for (int p = 0; p < 4; ++p) {
            ss = fmaf(a[2 * p], a[2 * p], fmaf(a[2 * p + 1], a[2 * p + 1], ss));
            float a0 = isx ? a[2 * p] * L2E     : a[2 * p];
            float a1 = isx ? a[2 * p + 1] * L2E : a[2 * p + 1];
            unsigned short h0 = f2h(a0), h1 = f2h(a1);
            unsigned short l0 = f2h(a0 - h2f(h0)), l1 = f2h(a1 - h2f(h1));
            hi[p] = (unsigned)h0 | ((unsigned)h1 << 16);
            lo[p] = (unsigned)l0 | ((unsigned)l1 << 16);
        }
        HI[c4] = make_uint4(hi[0], hi[1], hi[2], hi[3]);
        LO[c4] = make_uint4(lo[0], lo[1], lo[2], lo[3]);
    }

    short* base = (isx ? Acat : Bcat) + (size_t)rb * 4096 + l * 8;
    #pragma unroll
    for (int p = 0; p < 4; ++p) {
        *(uint4*)(base + p * 512)       = HI[p];               // phases 0..3
        *(uint4*)(base + (p + 4) * 512) = isx ? LO[p] : HI[p]; // phases 4..7
    }

    // lanes rp*4..rp*4+3 hold the 4 column-quarters of one row
    ss += __shfl_xor(ss, 1, 64);
    ss += __shfl_xor(ss, 2, 64);
    if ((l & 3) == 0) {
        if (isx) xc[row] = -0.5f * ss * L2E;
        else     mc[row] = (logf(w[row]) - 0.5f * ss) * L2E;
    }
}

// ---------------------------------------------------------------------------
// Main MFMA kernel — round-7 proven skeleton ((256,3), 2-buffer dbuf staging,
// prefetch issued AFTER the __syncthreads, one barrier per phase, swizzled
// conflict-free DMA->LDS layout), with K=256 fp16 (8 phases of BK=32).
// 128x128 tile, 4 waves 2x2, mfma_f32_16x16x32_f16.
// Epilogue: exp2(acc + xc + mc), width-16 shuffle reduce, partials store
// (no atomics); gmm_reduce sums the 64 column-strips.
// ---------------------------------------------------------------------------
__global__ __launch_bounds__(256, 3) void gmm_mfma(
    const short* __restrict__ Acat, const short* __restrict__ Bcat,
    const float* __restrict__ xc, const float* __restrict__ mc,
    float* __restrict__ partials)
{
    __shared__ __align__(16) short As[2][4096];   // 2 x 8 KB, 8 tiles x 512
    __shared__ __align__(16) short Bs[2][4096];   // 2 x 8 KB
    __shared__ __align__(16) float xcs[128];
    __shared__ float red[2][128];

    const int tid  = threadIdx.x;
    const int w    = tid >> 6, lane = tid & 63;
    const int wm   = w >> 1,   wn   = w & 1;
    const int quad = lane >> 4, col = lane & 15;
    const int m0   = blockIdx.x * 128;
    const int nb   = blockIdx.y * 128;

    // wave w stages row-blocks {w*2, w*2+1} of both A and B (contiguous 1KB)
    const short* ga0 = Acat + (size_t)(blockIdx.x * 8 + w * 2) * 4096 + lane * 8;
    const short* ga1 = ga0 + 4096;
    const short* gb0 = Bcat + (size_t)(blockIdx.y * 8 + w * 2) * 4096 + lane * 8;
    const short* gb1 = gb0 + 4096;
    const int lofs0 = w * 1024;        // tile (w*2)   * 512 shorts
    const int lofs1 = w * 1024 + 512;  // tile (w*2+1) * 512 shorts

    if (tid < 128) xcs[tid] = xc[m0 + tid];

    // stage phase 0 into buffer 0
    async16(&As[0][lofs0], ga0);
    async16(&As[0][lofs1], ga1);
    async16(&Bs[0][lofs0], gb0);
    async16(&Bs[0][lofs1], gb1);

    f32x4 acc[4][4];
    #pragma unroll
    for (int i = 0; i < 4; ++i)
        #pragma unroll
        for (int j = 0; j < 4; ++j)
            acc[i][j] = (f32x4){0.f, 0.f, 0.f, 0.f};

    // swizzled in-tile read offset (shorts): r'=col, g=quad
    const int rdo = col * 32 + ((quad + (col >> 1)) & 3) * 8;

    #pragma unroll 1
    for (int ks = 0; ks < 8; ++ks) {
        const int buf = ks & 1;
        __syncthreads();   // waits on staging issued one full phase ago
        if (ks < 7) {
            const int ko = (ks + 1) * 512;
            async16(&As[buf ^ 1][lofs0], ga0 + ko);
            async16(&As[buf ^ 1][lofs1], ga1 + ko);
            async16(&Bs[buf ^ 1][lofs0], gb0 + ko);
            async16(&Bs[buf ^ 1][lofs1], gb1 + ko);
        }

        f16x8 af[4];
        #pragma unroll
        for (int i = 0; i < 4; ++i)
            af[i] = *(const f16x8*)(&As[buf][(wm * 4 + i) * 512 + rdo]);
        #pragma unroll
        for (int j = 0; j < 4; ++j) {
            f16x8 bfr = *(const f16x8*)(&Bs[buf][(wn * 4 + j) * 512 + rdo]);
            #pragma unroll
            for (int i = 0; i < 4; ++i)
                acc[i][j] = __builtin_amdgcn_mfma_f32_16x16x32_f16(
                    af[i], bfr, acc[i][j], 0, 0, 0);
        }
    }

    // epilogue: C/D layout col = lane&15, row = quad*4 + reg
    float mcv[4];
    #pragma unroll
    for (int j = 0; j < 4; ++j) mcv[j] = mc[nb + wn * 64 + j * 16 + col];

    #pragma unroll
    for (int i = 0; i < 4; ++i) {
        float4 xv = *(const float4*)&xcs[wm * 64 + i * 16 + quad * 4];
        float xa[4] = {xv.x, xv.y, xv.z, xv.w};
        #pragma unroll
        for (int r = 0; r < 4; ++r) {
            float s = 0.f;
            #pragma unroll
            for (int j = 0; j < 4; ++j)
                s += __builtin_exp2f(acc[i][j][r] + xa[r] + mcv[j]);
            s += __shfl_xor(s, 1, 16);
            s += __shfl_xor(s, 2, 16);
            s += __shfl_xor(s, 4, 16);
            s += __shfl_xor(s, 8, 16);
            if (col == 0) red[wn][wm * 64 + i * 16 + quad * 4 + r] = s;
        }
    }
    __syncthreads();
    if (tid < 128)
        partials[(size_t)blockIdx.y * MM + m0 + tid] = red[0][tid] + red[1][tid];
}

__global__ __launch_bounds__(256) void gmm_reduce(
    const float* __restrict__ partials, float* __restrict__ out)
{
    int m = blockIdx.x * 256 + threadIdx.x;
    float s = 0.f;
    #pragma unroll 8
    for (int k = 0; k < 64; ++k) s += partials[(size_t)k * MM + m];
    out[m] = COEF * s;
}

// ===========================================================================
// Fallback fp32 path (round-1) — only if ws_size is too small.
// ===========================================================================
__global__ __launch_bounds__(256) void gmm_prep(
    const float* __restrict__ x, const float* __restrict__ means,
    const float* __restrict__ w, float* __restrict__ xc, float* __restrict__ mc)
{
    int tid = blockIdx.x * 256 + threadIdx.x;
    if (tid < MM) {
        const float4* row = (const float4*)(x + (size_t)tid * DD);
        float ss = 0.f;
        #pragma unroll
        for (int i = 0; i < DD / 4; ++i) {
            float4 v = row[i];
            ss = fmaf(v.x, v.x, fmaf(v.y, v.y, fmaf(v.z, v.z, fmaf(v.w, v.w, ss))));
        }
        xc[tid] = -0.5f * ss * L2E;
    } else if (tid < MM + NN) {
        int n = tid - MM;
        const float4* row = (const float4*)(means + (size_t)n * DD);
        float ss = 0.f;
        #pragma unroll
        for (int i = 0; i < DD / 4; ++i) {
            float4 v = row[i];
            ss = fmaf(v.x, v.x, fmaf(v.y, v.y, fmaf(v.z, v.z, fmaf(v.w, v.w, ss))));
        }
        mc[n] = (logf(w[n]) - 0.5f * ss) * L2E;
    }
}

__global__ __launch_bounds__(256, 2) void gmm_main(
    const float* __restrict__ x, const float* __restrict__ means,
    const float* __restrict__ xc, const float* __restrict__ mc,
    float* __restrict__ out)
{
    __shared__ __align__(16) float Asm[128 * 128];
    __shared__ __align__(16) float Bsm[2][16 * 128];

    const int t   = threadIdx.x;
    const int tc  = t & 15;
    const int tr  = t >> 4;
    const int r0  = blockIdx.x * 128;
    const int nq0 = blockIdx.y * 2048;

    {
        float4 tmp[16];
        #pragma unroll
        for (int ii = 0; ii < 16; ++ii) {
            int idx = t + ii * 256;
            int r   = idx >> 5;
            int k0  = (idx & 31) << 2;
            tmp[ii] = *(const float4*)(x + (size_t)(r0 + r) * DD + k0);
        }
        #pragma unroll
        for (int ii = 0; ii < 16; ++ii) {
            int idx = t + ii * 256;
            int r   = idx >> 5;
            int k0  = (idx & 31) << 2;
            int rb  = r >> 3, rl = r & 7;
            float v[4] = {tmp[ii].x, tmp[ii].y, tmp[ii].z, tmp[ii].w};
            #pragma unroll
            for (int j = 0; j < 4; ++j) {
                int k = k0 + j;
                Asm[k * 128 + (((rb ^ (k & 15)) << 3) | rl)] = v[j];
            }
        }
    }

    float xcv[8];
    {
        float4 a = *(const float4*)(xc + r0 + tr * 8);
        float4 b = *(const float4*)(xc + r0 + tr * 8 + 4);
        xcv[0] = a.x; xcv[1] = a.y; xcv[2] = a.z; xcv[3] = a.w;
        xcv[4] = b.x; xcv[5] = b.y; xcv[6] = b.z; xcv[7] = b.w;
    }

    float rowAcc[8];
    #pragma unroll
    for (int i = 0; i < 8; ++i) rowAcc[i] = 0.f;

    for (int ntile = 0; ntile < 16; ++ntile) {
        const int nbase = nq0 + ntile * 128;

        float acc[8][8];
        #pragma unroll
        for (int i = 0; i < 8; ++i)
            #pragma unroll
            for (int j = 0; j < 8; ++j) acc[i][j] = 0.f;

        float4 ld[2];
        #pragma unroll
        for (int ii = 0; ii < 2; ++ii) {
            int flat = t + ii * 256;
            int nl   = flat >> 2;
            int kl   = (flat & 3) << 2;
            ld[ii] = *(const float4*)(means + (size_t)(nbase + nl) * DD + kl);
        }

        for (int ks = 0; ks < 8; ++ks) {
            const int buf = ks & 1;
            #pragma unroll
            for (int ii = 0; ii < 2; ++ii) {
                int flat = t + ii * 256;
                int nl   = flat >> 2;
                int k0   = (flat & 3) << 2;
                int nbk  = nl >> 3, nll = nl & 7;
                float v[4] = {ld[ii].x, ld[ii].y, ld[ii].z, ld[ii].w};
                #pragma unroll
                for (int j = 0; j < 4; ++j) {
                    int kl = k0 + j;
                    Bsm[buf][kl * 128 + (((nbk ^ kl) << 3) | nll)] = v[j];
                }
            }
            if (ks < 7) {
                #pragma unroll
                for (int ii = 0; ii < 2; ++ii) {
                    int flat = t + ii * 256;
                    int nl   = flat >> 2;
                    int kl   = (flat & 3) << 2;
                    ld[ii] = *(const float4*)(means + (size_t)(nbase + nl) * DD
                                              + (ks + 1) * 16 + kl);
                }
            }
            __syncthreads();

            #pragma unroll
            for (int kk = 0; kk < 16; ++kk) {
                const int k = ks * 16 + kk;
                const float* apx = &Asm[k * 128 + ((tr ^ kk) << 3)];
                float4 a0 = *(const float4*)apx;
                float4 a1 = *(const float4*)(apx + 4);
                const float* bpx = &Bsm[buf][kk * 128 + ((tc ^ kk) << 3)];
                float4 b0 = *(const float4*)bpx;
                float4 b1 = *(const float4*)(bpx + 4);
                float av[8] = {a0.x, a0.y, a0.z, a0.w, a1.x, a1.y, a1.z, a1.w};
                float bv[8] = {b0.x, b0.y, b0.z, b0.w, b1.x, b1.y, b1.z, b1.w};
                #pragma unroll
                for (int i = 0; i < 8; ++i)
                    #pragma unroll
                    for (int j = 0; j < 8; ++j)
                        acc[i][j] = fmaf(av[i], bv[j], acc[i][j]);
            }
        }

        float mcv[8];
        {
            float4 a = *(const float4*)(mc + nbase + tc * 8);
            float4 b = *(const float4*)(mc + nbase + tc * 8 + 4);
            mcv[0] = a.x; mcv[1] = a.y; mcv[2] = a.z; mcv[3] = a.w;
            mcv[4] = b.x; mcv[5] = b.y; mcv[6] = b.z; mcv[7] = b.w;
        }
        #pragma unroll
        for (int i = 0; i < 8; ++i) {
            float s = 0.f;
            #pragma unroll
            for (int j = 0; j < 8; ++j) {
                float arg = fmaf(acc[i][j], L2E, xcv[i] + mcv[j]);
                s += __builtin_exp2f(arg);
            }
            rowAcc[i] += s;
        }
    }

    #pragma unroll
    for (int i = 0; i < 8; ++i) {
        float v = rowAcc[i];
        v += __shfl_xor(v, 1, 16);
        v += __shfl_xor(v, 2, 16);
        v += __shfl_xor(v, 4, 16);
        v += __shfl_xor(v, 8, 16);
        if (tc == 0) atomicAdd(out + r0 + tr * 8 + i, COEF * v);
    }
}

extern "C" void kernel_launch(void* const* d_in, const int* in_sizes, int n_in,
                              void* d_out, int out_size, void* d_ws, size_t ws_size,
                              hipStream_t stream) {
    const float* x     = (const float*)d_in[0];
    const float* means = (const float*)d_in[1];
    const float* w     = (const float*)d_in[2];
    float* out = (float*)d_out;

    const size_t needA = (size_t)MM * 256 * sizeof(short);   // 8.4 MB
    const size_t needB = (size_t)NN * 256 * sizeof(short);   // 4.2 MB
    const size_t need  = needA + needB + (size_t)(MM + NN) * 4
                       + (size_t)64 * MM * 4;                // + partials 4 MB

    if (ws_size >= need) {
        short* Acat     = (short*)d_ws;
        short* Bcat     = Acat + (size_t)MM * 256;
        float* xc       = (float*)(Bcat + (size_t)NN * 256);
        float* mc       = xc + MM;
        float* partials = mc + NN;
        gmm_prep_f16<<<(MM + NN) / 64, 256, 0, stream>>>(x, means, w, Acat, Bcat, xc, mc);
        gmm_mfma<<<dim3(MM / 128, NN / 128), 256, 0, stream>>>(Acat, Bcat, xc, mc, partials);
        gmm_reduce<<<MM / 256, 256, 0, stream>>>(partials, out);
    } else {
        float* xc = (float*)d_ws;
        float* mc = xc + MM;
        hipMemsetAsync(out, 0, MM * sizeof(float), stream);
        gmm_prep<<<(MM + NN + 255) / 256, 256, 0, stream>>>(x, means, w, xc, mc);
        gmm_main<<<dim3(MM / 128, 4), 256, 0, stream>>>(x, means, xc, mc, out);
    }
}